// Round 3
// baseline (946.236 us; speedup 1.0000x reference)
//
#include <hip/hip_runtime.h>
#include <math.h>

#define H 512
#define B 32
#define S 1024
#define V 50000

// ---- workspace layout (float offsets) ---- (max used must stay <= 738304
// floats = proven ws capacity from rounds 1-2)
#define ZT_OFF   0         // zT [1536][32]
#define GT_OFF   49152     // gatesT [2048][32]
#define CT_OFF   114688    // cT [512][32]
#define Q_OFF    131072    // q [32][512]
#define YT_OFF   147456    // yT [1024][32]
#define SC_OFF   180224    // raw scores [32][1024]
#define CP_OFF   212992    // ctx partials [32][8][512]
#define MLP_OFF  344064    // (m,l) partials [32][8][2]
#define LSEP_OFF 737280    // lse partials [32][16][2]

// ---- d_out layout (float offsets) ----
#define DO_OUT   0         // [B][V] log-softmax
#define DO_CTX   1600000   // [B][H]
#define DO_H     1616384   // [B][H]
#define DO_C     1632768   // [B][H]
#define DO_ATTN  1649152   // [B][S]

// ============ k_prep: zT fill + q = we @ W_a (4-way k-split) ============
__global__ void k_prep(const int* __restrict__ wi, const float* __restrict__ lc,
                       const float* __restrict__ h0, const float* __restrict__ emb,
                       const float* __restrict__ Wa,
                       float* __restrict__ zT, float* __restrict__ q) {
    __shared__ float ech[512];
    __shared__ float red[4][64];
    int t = threadIdx.x;
    int b = blockIdx.x >> 3, hq = blockIdx.x & 7;
    int hl = t & 63, kg = t >> 6;
    int h = hq * 64 + hl;
    const float* er = emb + (long long)wi[b] * H;
    ech[t] = er[t];
    ech[256 + t] = er[256 + t];
    __syncthreads();
    if (kg == 0)      zT[h * 32 + b]           = ech[h];          // x part 1
    else if (kg == 1) zT[(H + h) * 32 + b]     = lc[b * H + h];   // x part 2
    else if (kg == 2) zT[(2 * H + h) * 32 + b] = h0[b * H + h];   // hidden
    float acc = 0.f;
    #pragma unroll 8
    for (int j = 0; j < 128; ++j) {
        int k = kg * 128 + j;
        acc += ech[k] * Wa[k * H + h];
    }
    red[kg][hl] = acc;
    __syncthreads();
    if (kg == 0) q[b * H + h] = red[0][hl] + red[1][hl] + red[2][hl] + red[3][hl];
}

// ============ k_gates: one block per gate row r; gatesT[r][b] ============
__global__ void k_gates(const float* __restrict__ zT, const float* __restrict__ Wih,
                        const float* __restrict__ Whh, const float* __restrict__ bih,
                        const float* __restrict__ bhh, float* __restrict__ gT) {
    __shared__ float red[8][32];
    int r = blockIdx.x;                 // 0..2047
    int t = threadIdx.x;
    int kg = t >> 5, b = t & 31;
    int k0 = kg * 192;
    const float* wih_r = Wih + (long long)r * 1024;
    const float* whh_r = Whh + (long long)r * 512;
    float acc = 0.f;
    int n_ih = (k0 < 1024) ? ((1024 - k0 < 192) ? (1024 - k0) : 192) : 0;
    #pragma unroll 4
    for (int j = 0; j < n_ih; ++j) {
        int k = k0 + j;
        acc += wih_r[k] * zT[k * 32 + b];
    }
    #pragma unroll 4
    for (int j = n_ih; j < 192; ++j) {
        int k = k0 + j;
        acc += whh_r[k - 1024] * zT[k * 32 + b];
    }
    red[kg][b] = acc;
    __syncthreads();
    if (t < 32) {
        float s = bih[r] + bhh[r];
        #pragma unroll
        for (int kk = 0; kk < 8; ++kk) s += red[kk][t];
        gT[r * 32 + t] = s;
    }
}

// ============ k_point: LSTM pointwise ============
__global__ void k_point(const float* __restrict__ gT, const float* __restrict__ cprev,
                        int layer, float* __restrict__ zT, float* __restrict__ cT,
                        float* __restrict__ yT, float* __restrict__ hOut,
                        float* __restrict__ cOut) {
    int t = blockIdx.x * 256 + threadIdx.x;      // 0..16383
    int b = t & 31, hi = t >> 5;
    float gi = gT[hi * 32 + b];
    float gf = gT[(512 + hi) * 32 + b];
    float gg = gT[(1024 + hi) * 32 + b];
    float go = gT[(1536 + hi) * 32 + b];
    float si = 1.f / (1.f + expf(-gi));
    float sf = 1.f / (1.f + expf(-gf));
    float so = 1.f / (1.f + expf(-go));
    float c = (layer == 0) ? cprev[b * H + hi] : cprev[hi * 32 + b];
    float cn = sf * c + si * tanhf(gg);
    float hn = so * tanhf(cn);
    if (layer == 0) {
        zT[hi * 32 + b] = hn;
        zT[(2 * H + hi) * 32 + b] = hn;
        cT[hi * 32 + b] = cn;
    } else {
        yT[hi * 32 + b] = hn;
        hOut[b * H + hi] = hn;
        cOut[b * H + hi] = cn;
    }
}

// ============ k_attn: fused scores+online-softmax+context partials ========
// grid 256 = b(32) x ch(8); each block: 128 s, 16 tiles of 8 s.
// enc read exactly once (67 MB total). Double-buffered LDS staging.
__global__ void k_attn(const float* __restrict__ q, const float* __restrict__ enc,
                       float* __restrict__ scg, float* __restrict__ cp,
                       float* __restrict__ mlp) {
    __shared__ float E[2][8 * 512];     // 32 KB
    __shared__ float sct[8];
    int t = threadIdx.x;
    int b = blockIdx.x >> 3, ch = blockIdx.x & 7;
    int s0 = ch * 128;

    // stage tile 0
    #pragma unroll
    for (int i = 0; i < 4; ++i) {
        int f = t * 4 + (i & 1) * 1024 + (i >> 1) * 2048;
        int sl = f >> 9, kk = f & 511;
        *(float4*)(&E[0][f]) =
            *(const float4*)(enc + ((long long)((s0 + sl) * 32 + b)) * H + kk);
    }

    float m = -1e30f, l = 0.f, c0 = 0.f, c1 = 0.f;
    int sl = t >> 5, lane = t & 31;
    const float4* q4 = (const float4*)(q + b * H);

    for (int tile = 0; tile < 16; ++tile) {
        int buf = tile & 1;
        __syncthreads();   // staged tile `buf` ready; prev readers of sct done
        // stage next tile into other buffer
        if (tile + 1 < 16) {
            #pragma unroll
            for (int i = 0; i < 4; ++i) {
                int f = t * 4 + (i & 1) * 1024 + (i >> 1) * 2048;
                int s2 = f >> 9, kk = f & 511;
                *(float4*)(&E[buf ^ 1][f]) =
                    *(const float4*)(enc + ((long long)((s0 + (tile + 1) * 8 + s2) * 32 + b)) * H + kk);
            }
        }
        // scores: 32 lanes per s; lane covers h = lane*4 + 128*j (conflict-free)
        float p = 0.f;
        const float4* Er = (const float4*)(&E[buf][sl * 512]);
        #pragma unroll
        for (int j = 0; j < 4; ++j) {
            float4 ev = Er[lane + 32 * j];
            float4 qv = q4[lane + 32 * j];
            p += ev.x * qv.x + ev.y * qv.y + ev.z * qv.z + ev.w * qv.w;
        }
        #pragma unroll
        for (int off = 16; off > 0; off >>= 1) p += __shfl_xor(p, off);
        if (lane == 0) sct[sl] = p;
        __syncthreads();
        // raw scores out (for exact final attn weights)
        if (t < 8) scg[b * S + s0 + tile * 8 + t] = sct[t];
        // online update (redundant per thread, identical)
        float tm = sct[0];
        #pragma unroll
        for (int j = 1; j < 8; ++j) tm = fmaxf(tm, sct[j]);
        float nm = fmaxf(m, tm);
        float alpha = expf(m - nm);
        l *= alpha; c0 *= alpha; c1 *= alpha;
        const float2* E2 = (const float2*)(&E[buf][0]);
        #pragma unroll
        for (int j = 0; j < 8; ++j) {
            float e = expf(sct[j] - nm);
            l += e;
            float2 ev = E2[j * 256 + t];
            c0 += e * ev.x;
            c1 += e * ev.y;
        }
        m = nm;
    }
    // write partials
    *(float2*)(cp + ((long long)(b * 8 + ch)) * 512 + 2 * t) = make_float2(c0, c1);
    if (t == 0) {
        mlp[(b * 8 + ch) * 2]     = m;
        mlp[(b * 8 + ch) * 2 + 1] = l;
    }
}

// ============ k_amerge: merge 8 chunk partials -> ctx, attn ============
__global__ void k_amerge(const float* __restrict__ cp, const float* __restrict__ mlp,
                         const float* __restrict__ scg, float* __restrict__ ctxOut,
                         float* __restrict__ yT, float* __restrict__ attn) {
    int b = blockIdx.x, t = threadIdx.x;
    float mc[8], lc8[8];
    #pragma unroll
    for (int c = 0; c < 8; ++c) { mc[c] = mlp[(b * 8 + c) * 2]; lc8[c] = mlp[(b * 8 + c) * 2 + 1]; }
    float M = mc[0];
    #pragma unroll
    for (int c = 1; c < 8; ++c) M = fmaxf(M, mc[c]);
    float L = 0.f, w[8];
    #pragma unroll
    for (int c = 0; c < 8; ++c) { w[c] = expf(mc[c] - M); L += lc8[c] * w[c]; }
    float invL = 1.f / L;
    float s0 = 0.f, s1 = 0.f;
    #pragma unroll
    for (int c = 0; c < 8; ++c) {
        float2 p = *(const float2*)(cp + ((long long)(b * 8 + c)) * 512 + 2 * t);
        s0 += w[c] * p.x;
        s1 += w[c] * p.y;
    }
    s0 *= invL; s1 *= invL;
    ctxOut[b * H + 2 * t]     = s0;
    ctxOut[b * H + 2 * t + 1] = s1;
    yT[(H + 2 * t) * 32 + b]     = s0;
    yT[(H + 2 * t + 1) * 32 + b] = s1;
    #pragma unroll
    for (int i = 0; i < 4; ++i) {
        int si = i * 256 + t;
        attn[b * S + si] = expf(scg[b * S + si] - M) * invL;
    }
}

// ============ k_gemm: logits[b][v] = y_b . Wout_v + bout_v ============
// Redesign (round 3): thread tile 8v x 2b, acc = 16 regs (no spill), W
// streamed from global with register double-buffer (no LDS, no syncthreads),
// y [1024][32] read from L2 (~50 MB L2 traffic, ~1.5 us). Wave = 16
// consecutive v rows -> 256 B unique/load-inst, ~2 KB in flight/phase.
// grid 391 x 256 thr = 1564 waves (6.1/CU).
__global__ __launch_bounds__(256, 1)
void k_gemm(const float* __restrict__ Wout, const float* __restrict__ yTg,
            const float* __restrict__ bout, float* __restrict__ out) {
    int tid = threadIdx.x;
    int vg = tid & 15;            // consecutive v within wave -> coalesced
    int bg = tid >> 4;            // 0..15 -> b = 2*bg, 2*bg+1
    int v0 = blockIdx.x * 128;
    const float2* yT2 = (const float2*)yTg;

    const float* Wp[8];
    #pragma unroll
    for (int d = 0; d < 8; ++d) {
        int v = v0 + vg + 16 * d;
        if (v >= V) v = V - 1;               // clamp loads; stores guarded
        Wp[d] = Wout + (long long)v * 1024;
    }
    float ax[8], ay[8];
    #pragma unroll
    for (int d = 0; d < 8; ++d) { ax[d] = 0.f; ay[d] = 0.f; }

    float4 wa[8], wb[8];
    #pragma unroll
    for (int d = 0; d < 8; ++d) wa[d] = *(const float4*)(Wp[d]);

    for (int kk = 0; kk < 1024; kk += 8) {
        // phase A: compute k = kk..kk+3 on wa, prefetch kk+4 -> wb
        #pragma unroll
        for (int d = 0; d < 8; ++d) wb[d] = *(const float4*)(Wp[d] + kk + 4);
        {
            float2 y0 = yT2[(kk + 0) * 16 + bg];
            float2 y1 = yT2[(kk + 1) * 16 + bg];
            float2 y2 = yT2[(kk + 2) * 16 + bg];
            float2 y3 = yT2[(kk + 3) * 16 + bg];
            #pragma unroll
            for (int d = 0; d < 8; ++d) {
                ax[d] += wa[d].x * y0.x + wa[d].y * y1.x + wa[d].z * y2.x + wa[d].w * y3.x;
                ay[d] += wa[d].x * y0.y + wa[d].y * y1.y + wa[d].z * y2.y + wa[d].w * y3.y;
            }
        }
        // phase B: compute k = kk+4..kk+7 on wb, prefetch kk+8 -> wa
        int kn = kk + 8;
        if (kn >= 1024) kn = 0;              // dummy reload (harmless, in-bounds)
        #pragma unroll
        for (int d = 0; d < 8; ++d) wa[d] = *(const float4*)(Wp[d] + kn);
        {
            float2 y0 = yT2[(kk + 4) * 16 + bg];
            float2 y1 = yT2[(kk + 5) * 16 + bg];
            float2 y2 = yT2[(kk + 6) * 16 + bg];
            float2 y3 = yT2[(kk + 7) * 16 + bg];
            #pragma unroll
            for (int d = 0; d < 8; ++d) {
                ax[d] += wb[d].x * y0.x + wb[d].y * y1.x + wb[d].z * y2.x + wb[d].w * y3.x;
                ay[d] += wb[d].x * y0.y + wb[d].y * y1.y + wb[d].z * y2.y + wb[d].w * y3.y;
            }
        }
    }
    int b0 = 2 * bg;
    #pragma unroll
    for (int d = 0; d < 8; ++d) {
        int v = v0 + vg + 16 * d;
        if (v < V) {
            float bo = bout[v];
            out[(long long)b0 * V + v]       = ax[d] + bo;
            out[(long long)(b0 + 1) * V + v] = ay[d] + bo;
        }
    }
}

// ============ k_lsep: per (b, chunk) online max/sumexp over logits ============
__global__ void k_lsep(const float* __restrict__ out, float* __restrict__ lsep) {
    __shared__ float rm[4], rl[4];
    int b = blockIdx.x >> 4, ch = blockIdx.x & 15;
    int t = threadIdx.x;
    int start = ch * 3125, end = start + 3125;
    float m = -1e30f, l = 0.f;
    for (int v = start + t; v < end; v += 256) {
        float x = out[(long long)b * V + v];
        float nm = fmaxf(m, x);
        l = l * expf(m - nm) + expf(x - nm);
        m = nm;
    }
    #pragma unroll
    for (int off = 32; off > 0; off >>= 1) {
        float m2 = __shfl_xor(m, off);
        float l2 = __shfl_xor(l, off);
        float nm = fmaxf(m, m2);
        l = l * expf(m - nm) + l2 * expf(m2 - nm);
        m = nm;
    }
    if ((t & 63) == 0) { rm[t >> 6] = m; rl[t >> 6] = l; }
    __syncthreads();
    if (t == 0) {
        m = rm[0]; l = rl[0];
        for (int i = 1; i < 4; ++i) {
            float nm = fmaxf(m, rm[i]);
            l = l * expf(m - nm) + rl[i] * expf(rm[i] - nm);
            m = nm;
        }
        lsep[(b * 16 + ch) * 2] = m;
        lsep[(b * 16 + ch) * 2 + 1] = l;
    }
}

// ============ k_final: merge lse chunks, out = logits - lse[b] ============
__global__ void k_final(const float* __restrict__ lsep, float* __restrict__ out) {
    __shared__ float lse[32];
    int t = threadIdx.x;
    if (t < 32) {
        float m = lsep[t * 32], l = lsep[t * 32 + 1];
        for (int i = 1; i < 16; ++i) {
            float m2 = lsep[t * 32 + i * 2], l2 = lsep[t * 32 + i * 2 + 1];
            float nm = fmaxf(m, m2);
            l = l * expf(m - nm) + l2 * expf(m2 - nm);
            m = nm;
        }
        lse[t] = m + logf(l);
    }
    __syncthreads();
    int idx0 = blockIdx.x * 2048 + t;
    #pragma unroll
    for (int i = 0; i < 8; ++i) {
        int idx = idx0 + i * 256;
        if (idx < B * V) {
            int b = idx / V;
            out[idx] -= lse[b];
        }
    }
}

extern "C" void kernel_launch(void* const* d_in, const int* in_sizes, int n_in,
                              void* d_out, int out_size, void* d_ws, size_t ws_size,
                              hipStream_t stream) {
    const int*   wi   = (const int*)d_in[0];
    const float* lc   = (const float*)d_in[1];
    const float* h0   = (const float*)d_in[2];
    const float* c0   = (const float*)d_in[3];
    const float* enc  = (const float*)d_in[4];
    const float* emb  = (const float*)d_in[5];
    const float* Wih  = (const float*)d_in[6];
    const float* Whh  = (const float*)d_in[7];
    const float* bih  = (const float*)d_in[8];
    const float* bhh  = (const float*)d_in[9];
    const float* Wa   = (const float*)d_in[10];
    // d_in[11] = b_a: cancels in softmax -> unused
    const float* Wout = (const float*)d_in[12];
    const float* bout = (const float*)d_in[13];
    float* out = (float*)d_out;
    float* ws  = (float*)d_ws;

    float* zT   = ws + ZT_OFF;
    float* gT   = ws + GT_OFF;
    float* cT   = ws + CT_OFF;
    float* q    = ws + Q_OFF;
    float* yT   = ws + YT_OFF;
    float* sc   = ws + SC_OFF;
    float* cp   = ws + CP_OFF;
    float* mlp  = ws + MLP_OFF;
    float* lsep = ws + LSEP_OFF;

    k_prep<<<256, 256, 0, stream>>>(wi, lc, h0, emb, Wa, zT, q);
    k_gates<<<2048, 256, 0, stream>>>(zT, Wih, Whh, bih, bhh, gT);
    k_point<<<64, 256, 0, stream>>>(gT, c0, 0, zT, cT, yT, out + DO_H, out + DO_C);
    k_gates<<<2048, 256, 0, stream>>>(zT, Wih, Whh, bih, bhh, gT);
    k_point<<<64, 256, 0, stream>>>(gT, cT, 1, zT, cT, yT, out + DO_H, out + DO_C);
    k_attn<<<256, 256, 0, stream>>>(q, enc, sc, cp, mlp);
    k_amerge<<<32, 256, 0, stream>>>(cp, mlp, sc, out + DO_CTX, yT, out + DO_ATTN);
    k_gemm<<<391, 256, 0, stream>>>(Wout, yT, bout, out + DO_OUT);
    k_lsep<<<512, 256, 0, stream>>>(out + DO_OUT, lsep);
    k_final<<<782, 256, 0, stream>>>(lsep, out + DO_OUT);
}